// Round 19
// baseline (265.370 us; speedup 1.0000x reference)
//
#include <hip/hip_runtime.h>

#define NTOK     131072
#define KCODES   1024
#define DIM      64
#define TAU_S    8e-4f
#define FLAG_CAP 16384

typedef unsigned short ushort_t;
typedef unsigned int uint_t;
typedef unsigned char uchar_t;
typedef __attribute__((ext_vector_type(8))) short short8;
typedef __attribute__((ext_vector_type(4))) float f32x4;
typedef __attribute__((ext_vector_type(2))) float nf32x2;

// ws layout (bytes):
//      0 : counts u32[1024]                 (..4096)
//   4096 : flag_cnt u32 (+pad)              (..4112)
//   4112 : lossA f32[8192] per-wave         (..36880)
//  36880 : lossB f64[1024] per-refine-wave  (..45072)
//  45072 : wsq f32[1024]                    (..49168)
//  49408 : Wst uchar[262144] staged W       (..311552)
// 311552 : flags int[16384]                 (..377088)
// 377088 : idx_g ushort[131072]             (..639232)
//
// Staged layout (r8): code k (g=k>>5, c=k&31), dim d (s=d>>3, p=d&7):
//   byte = g*8192 + half*4096 + s*512 + ((c ^ (s&3)))*16 + p*2
// Two consecutive groups (64 codes) = 16KB contiguous -> one LDS buffer.

// Inner-loop barrier: LDS-only ordering, stores/loads stay in flight.
// rule-18 fencing: sched_barrier(0) pins code across the inline lgkmcnt.
#define BAR_LDS() do {                                        \
    asm volatile("s_waitcnt lgkmcnt(0)" ::: "memory");        \
    __builtin_amdgcn_sched_barrier(0);                        \
    __builtin_amdgcn_s_barrier();                             \
    __builtin_amdgcn_sched_barrier(0);                        \
} while (0)

__device__ inline ushort_t f2bf(float f) {
    uint_t u = __float_as_uint(f);
    return (ushort_t)((u + 0x7FFFu + ((u >> 16) & 1u)) >> 16);
}
__device__ inline float bf2f(ushort_t h) { return __uint_as_float(((uint_t)h) << 16); }

__device__ inline void pack8(float4 p, float4 q, short8& h, short8& l) {
    float v[8] = {p.x, p.y, p.z, p.w, q.x, q.y, q.z, q.w};
#pragma unroll
    for (int j = 0; j < 8; ++j) {
        ushort_t hb = f2bf(v[j]);
        float hf = bf2f(hb);
        ushort_t lb = f2bf(v[j] - hf);
        h[j] = (short)hb;
        l[j] = (short)lb;
    }
}

// ---- prep: staged split of W, wsq, zero counters + flag counter ----
__global__ __launch_bounds__(256) void vq_prep(const float* __restrict__ W,
                                               uchar_t* __restrict__ Wst,
                                               float* __restrict__ wsq,
                                               uint_t* __restrict__ counts,
                                               uint_t* __restrict__ flag_cnt) {
    const int tid = threadIdx.x;
    if (blockIdx.x == 0) {
#pragma unroll
        for (int j = 0; j < 4; ++j) counts[tid * 4 + j] = 0u;
        if (tid == 0) *flag_cnt = 0u;
    }
    const int e = blockIdx.x * 256 + tid;      // 65536 elements
    const int k = e >> 6, d = e & 63;
    const float w = W[e];
    const ushort_t hb = f2bf(w);
    const float hf = bf2f(hb);
    const ushort_t lb = f2bf(w - hf);
    const int g = k >> 5, c = k & 31, s = d >> 3, p = d & 7;
    const size_t base = (size_t)g * 8192 + (size_t)s * 512
                      + (size_t)(c ^ (s & 3)) * 16 + (size_t)p * 2;
    *(ushort_t*)(Wst + base)        = hb;
    *(ushort_t*)(Wst + base + 4096) = lb;
    float sq = w * w;
#pragma unroll
    for (int off = 32; off >= 1; off >>= 1) sq += __shfl_xor(sq, off, 64);
    if ((tid & 63) == 0) wsq[e >> 6] = sq;
}

// ---- fused: 64 tok/block argmin scan, 64-code LDS buffers (15 barriers),
//      interleaved encodings zero-stream ----
__global__ __launch_bounds__(256) void vq_fused(
    const float* __restrict__ X, const uchar_t* __restrict__ Wst,
    const float* __restrict__ wsq_g, const float* __restrict__ W,
    float* __restrict__ out, ushort_t* __restrict__ idx_g,
    uint_t* __restrict__ counts, float* __restrict__ lossA,
    uint_t* __restrict__ flag_cnt, int* __restrict__ flags)
{
    const int tid   = threadIdx.x;
    const int lane  = tid & 63;
    const int wv    = tid >> 6;
    const int col16 = lane & 15;
    const int ks    = lane >> 4;
    const int TB    = blockIdx.x * 64;
    const int WB    = TB + wv * 16;

    __shared__ __align__(16) char sbuf[2][16384];   // two 64-code buffers
    __shared__ float s_xsq[4][16];
    __shared__ int   s_idx[64];

    float* enc = out + 2 + (size_t)NTOK * DIM + (size_t)TB * KCODES;

    // A: one 16-token tile per wave, bf16 hi/lo fragments
    short8 xh0, xh1, xl0, xl1;
    {
        const float* xr = X + (size_t)(WB + col16) * DIM + ks * 8;
        float4 a0 = *(const float4*)(xr);
        float4 a1 = *(const float4*)(xr + 4);
        float4 a2 = *(const float4*)(xr + 32);
        float4 a3 = *(const float4*)(xr + 36);
        float xsq = a0.x*a0.x + a0.y*a0.y + a0.z*a0.z + a0.w*a0.w
                  + a1.x*a1.x + a1.y*a1.y + a1.z*a1.z + a1.w*a1.w
                  + a2.x*a2.x + a2.y*a2.y + a2.z*a2.z + a2.w*a2.w
                  + a3.x*a3.x + a3.y*a3.y + a3.z*a3.z + a3.w*a3.w;
        xsq += __shfl_xor(xsq, 16, 64);
        xsq += __shfl_xor(xsq, 32, 64);
        if (lane < 16) s_xsq[wv][lane] = xsq;   // same-wave produce/consume
        pack8(a0, a1, xh0, xl0);
        pack8(a2, a3, xh1, xl1);
    }

    // stage buffer 0 (64 codes = 16KB): 4 x 16B per thread
    short8 p0, p1, p2, p3;
    {
        const short8* src = (const short8*)(Wst + (size_t)tid * 16);
        p0 = src[0]; p1 = src[256]; p2 = src[512]; p3 = src[768];
        short8* dst = (short8*)(&sbuf[0][tid * 16]);
        dst[0] = p0; dst[256] = p1; dst[512] = p2; dst[768] = p3;
    }
    __syncthreads();   // prologue: full sync (once)

    float m1[4], m2[4]; int i1[4];
#pragma unroll
    for (int r = 0; r < 4; ++r) { m1[r] = -3.4e38f; m2[r] = -3.4e38f; i1[r] = 0; }

    const int rb = ks * 512 + ((col16 ^ ks) * 16);
    const nf32x2 zz = {0.f, 0.f};
    const f32x4 zero4 = {0.f, 0.f, 0.f, 0.f};

    for (int gp = 0; gp < 16; ++gp) {               // 16 intervals, 15 barriers
        const int cb = gp * 64;
        const int b  = gp & 1;
        if (gp < 15) {                              // prefetch next 64-code buffer
            const short8* src = (const short8*)(Wst + (size_t)(gp + 1) * 16384 + (size_t)tid * 16);
            p0 = src[0]; p1 = src[256]; p2 = src[512]; p3 = src[768];
        }
        // zero-stream 16KB of this block's 256KB encodings chunk
        {
            float* zp = enc + gp * 4096 + tid * 16;
#pragma unroll
            for (int i = 0; i < 8; ++i)
                *(nf32x2*)(zp + 2 * i) = zz;
        }
        const char* buf = sbuf[b];
#pragma unroll
        for (int j2 = 0; j2 < 4; ++j2) {            // 4 subgroups of 16 codes
            const int off = (j2 >> 1) * 8192 + rb + (j2 & 1) * 256;
            short8 bh0 = *(const short8*)(buf + off);
            short8 bh1 = *(const short8*)(buf + off + 2048);
            short8 bl0 = *(const short8*)(buf + off + 4096);
            short8 bl1 = *(const short8*)(buf + off + 6144);
            const float c0 = -0.5f * wsq_g[cb + j2 * 16 + col16];
            f32x4 aA, aB;                           // two independent 3-deep chains
            aA[0] = c0; aA[1] = c0; aA[2] = c0; aA[3] = c0;
            aB = zero4;
            aA = __builtin_amdgcn_mfma_f32_16x16x32_bf16(xh0, bh0, aA, 0, 0, 0);
            aB = __builtin_amdgcn_mfma_f32_16x16x32_bf16(xh1, bh1, aB, 0, 0, 0);
            aA = __builtin_amdgcn_mfma_f32_16x16x32_bf16(xh0, bl0, aA, 0, 0, 0);
            aB = __builtin_amdgcn_mfma_f32_16x16x32_bf16(xh1, bl1, aB, 0, 0, 0);
            aA = __builtin_amdgcn_mfma_f32_16x16x32_bf16(xl0, bh0, aA, 0, 0, 0);
            aB = __builtin_amdgcn_mfma_f32_16x16x32_bf16(xl1, bh1, aB, 0, 0, 0);
            const int cc = cb + j2 * 16 + col16;
#pragma unroll
            for (int r = 0; r < 4; ++r) {
                float v = aA[r] + aB[r];
                bool gt = v > m1[r];                  // strict: ties keep lower idx
                m2[r] = __builtin_amdgcn_fmed3f(v, m1[r], m2[r]);  // 2nd-max (m1>=m2)
                i1[r] = gt ? cc : i1[r];
                m1[r] = fmaxf(v, m1[r]);
            }
        }
        if (gp < 15) {
            short8* dst = (short8*)(&sbuf[b ^ 1][tid * 16]);
            dst[0] = p0; dst[256] = p1; dst[512] = p2; dst[768] = p3;
            BAR_LDS();                              // LDS-only: no vmcnt drain
        }
    }

    // merge top-2 across the 16 code-residue lanes of each ks group
#pragma unroll
    for (int mask = 1; mask <= 8; mask <<= 1) {
#pragma unroll
        for (int r = 0; r < 4; ++r) {
            float v1 = __shfl_xor(m1[r], mask, 64);
            int   j1 = __shfl_xor(i1[r], mask, 64);
            float v2 = __shfl_xor(m2[r], mask, 64);
            bool take = (v1 > m1[r]) || (v1 == m1[r] && j1 < i1[r]);
            m2[r] = take ? fmaxf(m1[r], v2) : fmaxf(v1, m2[r]);
            m1[r] = take ? v1 : m1[r];
            i1[r] = take ? j1 : i1[r];
        }
    }

    float lsum = 0.f;
    if (col16 == 0) {
#pragma unroll
        for (int r = 0; r < 4; ++r) {
            const int trow = ks * 4 + r;
            const int tok = WB + trow;
            s_idx[wv * 16 + trow] = i1[r];
            idx_g[tok] = (ushort_t)i1[r];
            atomicAdd(&counts[i1[r]], 1u);
            if (m1[r] - m2[r] < TAU_S) {
                uint_t pos = atomicAdd(flag_cnt, 1u);     // r8 A/B: harmless
                if (pos < FLAG_CAP) flags[pos] = tok;
                else lsum += s_xsq[wv][trow] - 2.f * m1[r];
            } else {
                lsum += s_xsq[wv][trow] - 2.f * m1[r];    // approx ||x-w||^2
            }
        }
    }
    lsum += __shfl_xor(lsum, 16, 64);
    lsum += __shfl_xor(lsum, 32, 64);
    if (lane == 0) lossA[blockIdx.x * 4 + wv] = lsum;
    __syncthreads();   // FULL sync: drains zero-store acks before the 1.0 scatter

    // ---- epilogue: scatter the 64 ones + quantized gather ----
    if (tid < 64)
        enc[(size_t)tid * KCODES + s_idx[tid]] = 1.f;

    for (int i = tid; i < 64 * DIM; i += 256) {
        const int r = i >> 6, c = i & 63;
        out[1 + (size_t)(TB + r) * DIM + c] = W[(size_t)s_idx[r] * DIM + c];
    }
}

// ---- refine: wave-per-flagged-token fp64 rescan (no block barriers) ----
__global__ __launch_bounds__(256) void vq_refine(
    const float* __restrict__ X, const float* __restrict__ W,
    float* __restrict__ out, uint_t* __restrict__ counts,
    double* __restrict__ lossB, const uint_t* __restrict__ flag_cnt,
    const int* __restrict__ flags, const ushort_t* __restrict__ idx_g)
{
    const int tid  = threadIdx.x;
    const int lane = tid & 63;
    const int wid  = blockIdx.x * 4 + (tid >> 6);   // 1024 waves
    uint_t n = *flag_cnt; if (n > FLAG_CAP) n = FLAG_CAP;

    double lcorr = 0.0;
    for (uint_t e = wid; e < n; e += 1024) {
        const int t   = flags[e];
        const int old = idx_g[t];

        float xf[DIM];
        {
            const float4* xr4 = (const float4*)(X + (size_t)t * DIM);
#pragma unroll
            for (int i = 0; i < 16; ++i) {
                float4 v = xr4[i];
                xf[4*i+0] = v.x; xf[4*i+1] = v.y; xf[4*i+2] = v.z; xf[4*i+3] = v.w;
            }
        }

        double best = 1e300; int bi = KCODES;
        for (int k = 0; k < 16; ++k) {
            const int c = (k << 6) + lane;          // ascending per lane
            const float* wr = W + (size_t)c * DIM;
            double dsum = 0.0;
#pragma unroll
            for (int d = 0; d < DIM; ++d) {
                double diff = (double)xf[d] - (double)wr[d];
                dsum += diff * diff;
            }
            if (dsum < best) { best = dsum; bi = c; }   // strict: lowest c wins
        }
#pragma unroll
        for (int mask = 1; mask <= 32; mask <<= 1) {
            double db = __shfl_xor(best, mask, 64);
            int    ib = __shfl_xor(bi, mask, 64);
            if (db < best || (db == best && ib < bi)) { best = db; bi = ib; }
        }
        out[1 + (size_t)t * DIM + lane] = W[(size_t)bi * DIM + lane];
        if (lane == 0) {
            lcorr += best;
            if (bi != old) {
                atomicSub(&counts[old], 1u);
                atomicAdd(&counts[bi], 1u);
                float* encp = out + 2 + (size_t)NTOK * DIM + (size_t)t * KCODES;
                encp[old] = 0.f;
                encp[bi]  = 1.f;
            }
        }
    }
    if (lane == 0) lossB[wid] = lcorr;   // all 1024 waves write (0 if idle)
}

__global__ __launch_bounds__(256) void vq_finalize(
    const uint_t* __restrict__ counts, const float* __restrict__ lossA,
    const double* __restrict__ lossB, float* __restrict__ out)
{
    int tid = threadIdx.x;
    double ls = 0.0;                       // deterministic fixed-tree reduction
    for (int i = tid; i < 8192; i += 256) ls += (double)lossA[i];
    for (int i = tid; i < 1024; i += 256) ls += lossB[i];
    float h = 0.f;
    for (int i = tid; i < KCODES; i += 256) {
        float p = (float)counts[i] * (1.0f / (float)NTOK);
        h += p * logf(p + 1e-10f);
    }
    __shared__ double dred[256];
    dred[tid] = ls;
    __syncthreads();
#pragma unroll
    for (int s = 128; s >= 1; s >>= 1) {
        if (tid < s) dred[tid] += dred[tid + s];
        __syncthreads();
    }
    __shared__ float red[4];
#pragma unroll
    for (int off = 32; off >= 1; off >>= 1) h += __shfl_down(h, off, 64);
    if ((tid & 63) == 0) red[tid >> 6] = h;
    __syncthreads();
    if (tid == 0) {
        float ht = red[0] + red[1] + red[2] + red[3];
        out[(size_t)NTOK * DIM + 1] = expf(-ht);                        // perplexity
        out[0] = 0.25f * (float)(dred[0] / ((double)NTOK * DIM));       // loss
    }
}

extern "C" void kernel_launch(void* const* d_in, const int* in_sizes, int n_in,
                              void* d_out, int out_size, void* d_ws, size_t ws_size,
                              hipStream_t stream) {
    const float* X = (const float*)d_in[0];
    const float* W = (const float*)d_in[1];
    float* out = (float*)d_out;
    uint_t*   counts   = (uint_t*)d_ws;
    uint_t*   flag_cnt = (uint_t*)((char*)d_ws + 4096);
    float*    lossA    = (float*)((char*)d_ws + 4112);
    double*   lossB    = (double*)((char*)d_ws + 36880);
    float*    wsq      = (float*)((char*)d_ws + 45072);
    uchar_t*  Wst      = (uchar_t*)((char*)d_ws + 49408);
    int*      flags    = (int*)((char*)d_ws + 311552);
    ushort_t* idx_g    = (ushort_t*)((char*)d_ws + 377088);

    vq_prep<<<256, 256, 0, stream>>>(W, Wst, wsq, counts, flag_cnt);
    vq_fused<<<NTOK / 64, 256, 0, stream>>>(X, Wst, wsq, W, out, idx_g,
                                            counts, lossA, flag_cnt, flags);
    vq_refine<<<256, 256, 0, stream>>>(X, W, out, counts, lossB,
                                       flag_cnt, flags, idx_g);
    vq_finalize<<<1, 256, 0, stream>>>(counts, lossA, lossB, out);
}

// Round 20
// 204.467 us; speedup vs baseline: 1.2979x; 1.2979x over previous
//
#include <hip/hip_runtime.h>

#define NTOK     131072
#define KCODES   1024
#define DIM      64
#define TAU_S    8e-4f
#define FLAG_CAP 16384

typedef unsigned short ushort_t;
typedef unsigned int uint_t;
typedef unsigned char uchar_t;
typedef __attribute__((ext_vector_type(8))) short short8;
typedef __attribute__((ext_vector_type(4))) float f32x4;
typedef __attribute__((ext_vector_type(2))) float nf32x2;

// ws layout (bytes):
//      0 : counts u32[1024]                 (..4096)
//   4096 : flag_cnt u32 (+pad)              (..4112)
//   4112 : lossA f32[8192] per-wave         (..36880)
//  36880 : lossB f64[1024] per-refine-wave  (..45072)
//  45072 : wsq f32[1024]                    (..49168)
//  49408 : Wst uchar[262144] staged W       (..311552)
// 311552 : flags int[16384]                 (..377088)
// 377088 : idx_g ushort[131072]             (..639232)
//
// Staged layout (r8): code k (g=k>>5, c=k&31), dim d (s=d>>3, p=d&7):
//   byte = g*8192 + half*4096 + s*512 + ((c ^ (s&3)))*16 + p*2

// Inner-loop barrier: LDS-only ordering, stores/loads stay in flight.
// rule-18 fencing: sched_barrier(0) pins code across the inline lgkmcnt.
#define BAR_LDS() do {                                        \
    asm volatile("s_waitcnt lgkmcnt(0)" ::: "memory");        \
    __builtin_amdgcn_sched_barrier(0);                        \
    __builtin_amdgcn_s_barrier();                             \
    __builtin_amdgcn_sched_barrier(0);                        \
} while (0)

__device__ inline ushort_t f2bf(float f) {
    uint_t u = __float_as_uint(f);
    return (ushort_t)((u + 0x7FFFu + ((u >> 16) & 1u)) >> 16);
}
__device__ inline float bf2f(ushort_t h) { return __uint_as_float(((uint_t)h) << 16); }

__device__ inline void pack8(float4 p, float4 q, short8& h, short8& l) {
    float v[8] = {p.x, p.y, p.z, p.w, q.x, q.y, q.z, q.w};
#pragma unroll
    for (int j = 0; j < 8; ++j) {
        ushort_t hb = f2bf(v[j]);
        float hf = bf2f(hb);
        ushort_t lb = f2bf(v[j] - hf);
        h[j] = (short)hb;
        l[j] = (short)lb;
    }
}

// ---- prep: staged split of W, wsq, zero counters + flag counter ----
__global__ __launch_bounds__(256) void vq_prep(const float* __restrict__ W,
                                               uchar_t* __restrict__ Wst,
                                               float* __restrict__ wsq,
                                               uint_t* __restrict__ counts,
                                               uint_t* __restrict__ flag_cnt) {
    const int tid = threadIdx.x;
    if (blockIdx.x == 0) {
#pragma unroll
        for (int j = 0; j < 4; ++j) counts[tid * 4 + j] = 0u;
        if (tid == 0) *flag_cnt = 0u;
    }
    const int e = blockIdx.x * 256 + tid;      // 65536 elements
    const int k = e >> 6, d = e & 63;
    const float w = W[e];
    const ushort_t hb = f2bf(w);
    const float hf = bf2f(hb);
    const ushort_t lb = f2bf(w - hf);
    const int g = k >> 5, c = k & 31, s = d >> 3, p = d & 7;
    const size_t base = (size_t)g * 8192 + (size_t)s * 512
                      + (size_t)(c ^ (s & 3)) * 16 + (size_t)p * 2;
    *(ushort_t*)(Wst + base)        = hb;
    *(ushort_t*)(Wst + base + 4096) = lb;
    float sq = w * w;
#pragma unroll
    for (int off = 32; off >= 1; off >>= 1) sq += __shfl_xor(sq, off, 64);
    if ((tid & 63) == 0) wsq[e >> 6] = sq;
}

// ---- fused: argmin scan + interleaved zero-stream; inner barriers LDS-only ----
__global__ __launch_bounds__(256) void vq_fused(
    const float* __restrict__ X, const uchar_t* __restrict__ Wst,
    const float* __restrict__ wsq_g, const float* __restrict__ W,
    float* __restrict__ out, ushort_t* __restrict__ idx_g,
    uint_t* __restrict__ counts, float* __restrict__ lossA,
    uint_t* __restrict__ flag_cnt, int* __restrict__ flags)
{
    const int tid   = threadIdx.x;
    const int lane  = tid & 63;
    const int wv    = tid >> 6;
    const int col16 = lane & 15;
    const int ks    = lane >> 4;
    const int TB    = blockIdx.x * 64;
    const int WB    = TB + wv * 16;

    __shared__ __align__(16) char sbuf[2][8192];
    __shared__ float s_xsq[4][16];
    __shared__ int   s_idx[64];

    float* enc = out + 2 + (size_t)NTOK * DIM + (size_t)TB * KCODES;

    // A: one 16-token tile per wave, bf16 hi/lo fragments
    short8 xh0, xh1, xl0, xl1;
    {
        const float* xr = X + (size_t)(WB + col16) * DIM + ks * 8;
        float4 a0 = *(const float4*)(xr);
        float4 a1 = *(const float4*)(xr + 4);
        float4 a2 = *(const float4*)(xr + 32);
        float4 a3 = *(const float4*)(xr + 36);
        float xsq = a0.x*a0.x + a0.y*a0.y + a0.z*a0.z + a0.w*a0.w
                  + a1.x*a1.x + a1.y*a1.y + a1.z*a1.z + a1.w*a1.w
                  + a2.x*a2.x + a2.y*a2.y + a2.z*a2.z + a2.w*a2.w
                  + a3.x*a3.x + a3.y*a3.y + a3.z*a3.z + a3.w*a3.w;
        xsq += __shfl_xor(xsq, 16, 64);
        xsq += __shfl_xor(xsq, 32, 64);
        if (lane < 16) s_xsq[wv][lane] = xsq;   // same-wave produce/consume
        pack8(a0, a1, xh0, xl0);
        pack8(a2, a3, xh1, xl1);
    }

    short8 p0, p1;
    {
        const short8* src = (const short8*)(Wst + (size_t)tid * 16);
        p0 = src[0]; p1 = src[256];
        short8* dst = (short8*)(&sbuf[0][tid * 16]);
        dst[0] = p0; dst[256] = p1;
    }
    __syncthreads();   // prologue: full sync (once)

    float m1[4], m2[4]; int i1[4];
#pragma unroll
    for (int r = 0; r < 4; ++r) { m1[r] = -3.4e38f; m2[r] = -3.4e38f; i1[r] = 0; }

    const int rb = ks * 512 + ((col16 ^ ks) * 16);
    const nf32x2 zz = {0.f, 0.f};
    const f32x4 zero4 = {0.f, 0.f, 0.f, 0.f};

    for (int g = 0; g < 32; ++g) {
        const int cb = g * 32;
        const int b  = g & 1;
        const float c0a = -0.5f * wsq_g[cb + col16];
        const float c0b = -0.5f * wsq_g[cb + 16 + col16];
        if (g < 31) {                              // prefetch next group from L2
            const short8* src = (const short8*)(Wst + (size_t)(g + 1) * 8192 + (size_t)tid * 16);
            p0 = src[0]; p1 = src[256];
        }
        // zero-stream 8KB of this block's encodings chunk (data-independent;
        // acks NOT drained at inner barriers -> flows freely under the scan)
        {
            float* zp = enc + g * 2048 + tid * 8;
            *(nf32x2*)(zp)     = zz;
            *(nf32x2*)(zp + 2) = zz;
            *(nf32x2*)(zp + 4) = zz;
            *(nf32x2*)(zp + 6) = zz;
        }
        const char* buf = sbuf[b];
#pragma unroll
        for (int j = 0; j < 2; ++j) {
            const int off = rb + j * 256;
            short8 bh0 = *(const short8*)(buf + off);
            short8 bh1 = *(const short8*)(buf + off + 2048);
            short8 bl0 = *(const short8*)(buf + off + 4096);
            short8 bl1 = *(const short8*)(buf + off + 6144);
            const float c0 = j ? c0b : c0a;
            // two independent 3-deep MFMA chains (k-half split)
            f32x4 aA, aB;
            aA[0] = c0; aA[1] = c0; aA[2] = c0; aA[3] = c0;
            aB = zero4;
            aA = __builtin_amdgcn_mfma_f32_16x16x32_bf16(xh0, bh0, aA, 0, 0, 0);
            aB = __builtin_amdgcn_mfma_f32_16x16x32_bf16(xh1, bh1, aB, 0, 0, 0);
            aA = __builtin_amdgcn_mfma_f32_16x16x32_bf16(xh0, bl0, aA, 0, 0, 0);
            aB = __builtin_amdgcn_mfma_f32_16x16x32_bf16(xh1, bl1, aB, 0, 0, 0);
            aA = __builtin_amdgcn_mfma_f32_16x16x32_bf16(xl0, bh0, aA, 0, 0, 0);
            aB = __builtin_amdgcn_mfma_f32_16x16x32_bf16(xl1, bh1, aB, 0, 0, 0);
            const int cc = cb + j * 16 + col16;
#pragma unroll
            for (int r = 0; r < 4; ++r) {
                float v = aA[r] + aB[r];
                bool gt = v > m1[r];                  // strict: ties keep lower idx
                m2[r] = __builtin_amdgcn_fmed3f(v, m1[r], m2[r]);  // 2nd-max (m1>=m2)
                i1[r] = gt ? cc : i1[r];
                m1[r] = fmaxf(v, m1[r]);
            }
        }
        if (g < 31) {
            short8* dst = (short8*)(&sbuf[b ^ 1][tid * 16]);
            dst[0] = p0; dst[256] = p1;
            BAR_LDS();                              // LDS-only: no vmcnt drain
        }
    }

    // merge top-2 across the 16 code-residue lanes of each ks group
#pragma unroll
    for (int mask = 1; mask <= 8; mask <<= 1) {
#pragma unroll
        for (int r = 0; r < 4; ++r) {
            float v1 = __shfl_xor(m1[r], mask, 64);
            int   j1 = __shfl_xor(i1[r], mask, 64);
            float v2 = __shfl_xor(m2[r], mask, 64);
            bool take = (v1 > m1[r]) || (v1 == m1[r] && j1 < i1[r]);
            m2[r] = take ? fmaxf(m1[r], v2) : fmaxf(v1, m2[r]);
            m1[r] = take ? v1 : m1[r];
            i1[r] = take ? j1 : i1[r];
        }
    }

    float lsum = 0.f;
    if (col16 == 0) {
#pragma unroll
        for (int r = 0; r < 4; ++r) {
            const int trow = ks * 4 + r;
            const int tok = WB + trow;
            s_idx[wv * 16 + trow] = i1[r];
            idx_g[tok] = (ushort_t)i1[r];
            atomicAdd(&counts[i1[r]], 1u);
            if (m1[r] - m2[r] < TAU_S) {
                uint_t pos = atomicAdd(flag_cnt, 1u);     // r8 A/B: harmless
                if (pos < FLAG_CAP) flags[pos] = tok;
                else lsum += s_xsq[wv][trow] - 2.f * m1[r];
            } else {
                lsum += s_xsq[wv][trow] - 2.f * m1[r];    // approx ||x-w||^2
            }
        }
    }
    lsum += __shfl_xor(lsum, 16, 64);
    lsum += __shfl_xor(lsum, 32, 64);
    if (lane == 0) lossA[blockIdx.x * 4 + wv] = lsum;
    __syncthreads();   // FULL sync: drains zero-store acks before the 1.0 scatter

    // ---- epilogue: scatter the 64 ones + quantized gather ----
    if (tid < 64)
        enc[(size_t)tid * KCODES + s_idx[tid]] = 1.f;

    for (int i = tid; i < 64 * DIM; i += 256) {
        const int r = i >> 6, c = i & 63;
        out[1 + (size_t)(TB + r) * DIM + c] = W[(size_t)s_idx[r] * DIM + c];
    }
}

// ---- refine: wave-per-flagged-token fp64 rescan (no block barriers) ----
__global__ __launch_bounds__(256) void vq_refine(
    const float* __restrict__ X, const float* __restrict__ W,
    float* __restrict__ out, uint_t* __restrict__ counts,
    double* __restrict__ lossB, const uint_t* __restrict__ flag_cnt,
    const int* __restrict__ flags, const ushort_t* __restrict__ idx_g)
{
    const int tid  = threadIdx.x;
    const int lane = tid & 63;
    const int wid  = blockIdx.x * 4 + (tid >> 6);   // 1024 waves
    uint_t n = *flag_cnt; if (n > FLAG_CAP) n = FLAG_CAP;

    double lcorr = 0.0;
    for (uint_t e = wid; e < n; e += 1024) {
        const int t   = flags[e];
        const int old = idx_g[t];

        float xf[DIM];
        {
            const float4* xr4 = (const float4*)(X + (size_t)t * DIM);
#pragma unroll
            for (int i = 0; i < 16; ++i) {
                float4 v = xr4[i];
                xf[4*i+0] = v.x; xf[4*i+1] = v.y; xf[4*i+2] = v.z; xf[4*i+3] = v.w;
            }
        }

        double best = 1e300; int bi = KCODES;
        for (int k = 0; k < 16; ++k) {
            const int c = (k << 6) + lane;          // ascending per lane
            const float* wr = W + (size_t)c * DIM;
            double dsum = 0.0;
#pragma unroll
            for (int d = 0; d < DIM; ++d) {
                double diff = (double)xf[d] - (double)wr[d];
                dsum += diff * diff;
            }
            if (dsum < best) { best = dsum; bi = c; }   // strict: lowest c wins
        }
#pragma unroll
        for (int mask = 1; mask <= 32; mask <<= 1) {
            double db = __shfl_xor(best, mask, 64);
            int    ib = __shfl_xor(bi, mask, 64);
            if (db < best || (db == best && ib < bi)) { best = db; bi = ib; }
        }
        out[1 + (size_t)t * DIM + lane] = W[(size_t)bi * DIM + lane];
        if (lane == 0) {
            lcorr += best;
            if (bi != old) {
                atomicSub(&counts[old], 1u);
                atomicAdd(&counts[bi], 1u);
                float* encp = out + 2 + (size_t)NTOK * DIM + (size_t)t * KCODES;
                encp[old] = 0.f;
                encp[bi]  = 1.f;
            }
        }
    }
    if (lane == 0) lossB[wid] = lcorr;   // all 1024 waves write (0 if idle)
}

__global__ __launch_bounds__(256) void vq_finalize(
    const uint_t* __restrict__ counts, const float* __restrict__ lossA,
    const double* __restrict__ lossB, float* __restrict__ out)
{
    int tid = threadIdx.x;
    double ls = 0.0;                       // deterministic fixed-tree reduction
    for (int i = tid; i < 8192; i += 256) ls += (double)lossA[i];
    for (int i = tid; i < 1024; i += 256) ls += lossB[i];
    float h = 0.f;
    for (int i = tid; i < KCODES; i += 256) {
        float p = (float)counts[i] * (1.0f / (float)NTOK);
        h += p * logf(p + 1e-10f);
    }
    __shared__ double dred[256];
    dred[tid] = ls;
    __syncthreads();
#pragma unroll
    for (int s = 128; s >= 1; s >>= 1) {
        if (tid < s) dred[tid] += dred[tid + s];
        __syncthreads();
    }
    __shared__ float red[4];
#pragma unroll
    for (int off = 32; off >= 1; off >>= 1) h += __shfl_down(h, off, 64);
    if ((tid & 63) == 0) red[tid >> 6] = h;
    __syncthreads();
    if (tid == 0) {
        float ht = red[0] + red[1] + red[2] + red[3];
        out[(size_t)NTOK * DIM + 1] = expf(-ht);                        // perplexity
        out[0] = 0.25f * (float)(dred[0] / ((double)NTOK * DIM));       // loss
    }
}

extern "C" void kernel_launch(void* const* d_in, const int* in_sizes, int n_in,
                              void* d_out, int out_size, void* d_ws, size_t ws_size,
                              hipStream_t stream) {
    const float* X = (const float*)d_in[0];
    const float* W = (const float*)d_in[1];
    float* out = (float*)d_out;
    uint_t*   counts   = (uint_t*)d_ws;
    uint_t*   flag_cnt = (uint_t*)((char*)d_ws + 4096);
    float*    lossA    = (float*)((char*)d_ws + 4112);
    double*   lossB    = (double*)((char*)d_ws + 36880);
    float*    wsq      = (float*)((char*)d_ws + 45072);
    uchar_t*  Wst      = (uchar_t*)((char*)d_ws + 49408);
    int*      flags    = (int*)((char*)d_ws + 311552);
    ushort_t* idx_g    = (ushort_t*)((char*)d_ws + 377088);

    vq_prep<<<256, 256, 0, stream>>>(W, Wst, wsq, counts, flag_cnt);
    vq_fused<<<NTOK / 64, 256, 0, stream>>>(X, Wst, wsq, W, out, idx_g,
                                            counts, lossA, flag_cnt, flags);
    vq_refine<<<256, 256, 0, stream>>>(X, W, out, counts, lossB,
                                       flag_cnt, flags, idx_g);
    vq_finalize<<<1, 256, 0, stream>>>(counts, lossA, lossB, out);
}